// Round 13
// baseline (57.558 us; speedup 1.0000x reference)
//
#include <hip/hip_runtime.h>
#include <hip/hip_bf16.h>
#include <hip/hip_fp16.h>

#define B_   4
#define N_   1024
#define H_   16
#define HID_ 64
#define TI   16
#define JH   256    // j-chunk per block (4 waves x 64 j)
#define PST  72     // bounce plane stride in floats (bank-balanced, 16B aligned)

typedef float    f32x4  __attribute__((ext_vector_type(4)));
typedef __fp16   fp16x2 __attribute__((ext_vector_type(2)));
typedef _Float16 f16x8  __attribute__((ext_vector_type(8)));
typedef unsigned int u32;

union F16x8U { u32 u[4]; f16x8 v; };

static __device__ __forceinline__ u32 pk(float a, float b) {
    union { fp16x2 f; u32 u; } r;
    r.f = __builtin_amdgcn_cvt_pkrtz(a, b);
    return r.u;
}
static __device__ __forceinline__ u32 pkadd_relu(u32 a, u32 b) {
    union { u32 u; fp16x2 f; } x, y, r;
    x.u = a; y.u = b;
    fp16x2 z = { (__fp16)0.f, (__fp16)0.f };
    fp16x2 s = x.f + y.f;
    r.f = __builtin_elementwise_max(s, z);
    return r.u;
}
static __device__ __forceinline__ u32 pkcvt_relu(float a, float b) {
    union { fp16x2 f; u32 u; } r;
    fp16x2 z = { (__fp16)0.f, (__fp16)0.f };
    fp16x2 s = __builtin_amdgcn_cvt_pkrtz(a, b);
    r.f = __builtin_elementwise_max(s, z);
    return r.u;
}

__global__ __launch_bounds__(256, 3) void RelativePositionalBias_kernel(
    const float* __restrict__ pos,  // (B,N,2)
    const int*   __restrict__ mask, // (B,N) 0/1
    const float* __restrict__ W1,   // (2,64)
    const float* __restrict__ b1,   // (64)
    const float* __restrict__ W2,   // (64,64)
    const float* __restrict__ b2,   // (64)
    const float* __restrict__ W3,   // (64,16)
    const float* __restrict__ b3,   // (16)
    float* __restrict__ out)        // (B,16,N,N)
{
    // 32KB: u_j staging (prologue) ALIASED with transpose bounce (main loop)
    __shared__ __align__(16) u32 shm[JH * 32];
    __shared__ __align__(16) u32 uinL[TI][32];
    u32 (*ujL)[32] = (u32(*)[32])shm;
    float* const bounce = (float*)shm;

    const int b   = blockIdx.z;
    const int i0  = blockIdx.y * TI;
    const int j0  = blockIdx.x * JH;
    const int tid = threadIdx.x;
    const int w = tid >> 6;      // wave 0..3, owns j-subrange [j0+64w, j0+64w+64)
    const int l = tid & 63;
    const int g = l >> 4;        // quarter-wave group 0..3
    const int c = l & 15;        // lane-within-group 0..15

    // ---- Stage packed-f16 u for 256 j-tokens + 16 i-tokens ----
    for (int it = tid; it < (JH + TI) * 8; it += 256) {
        int r  = it >> 3;
        int qq = it & 7;
        int k0 = qq * 8;
        int tok = (r < JH) ? (j0 + r) : (i0 + (r - JH));
        float2 p  = *(const float2*)&pos[(b * N_ + tok) * 2];
        float4 a0 = *(const float4*)&W1[k0];
        float4 a1 = *(const float4*)&W1[k0 + 4];
        float4 c0 = *(const float4*)&W1[HID_ + k0];
        float4 c1 = *(const float4*)&W1[HID_ + k0 + 4];
        float u0 = p.x*a0.x + p.y*c0.x, u1 = p.x*a0.y + p.y*c0.y;
        float u2 = p.x*a0.z + p.y*c0.z, u3 = p.x*a0.w + p.y*c0.w;
        float u4 = p.x*a1.x + p.y*c1.x, u5 = p.x*a1.y + p.y*c1.y;
        float u6 = p.x*a1.z + p.y*c1.z, u7 = p.x*a1.w + p.y*c1.w;
        const int col = ((qq ^ (r & 7)) << 2);   // XOR swizzle
        uint4 o;
        if (r < JH) {
            o.x = pk(u0, u1); o.y = pk(u2, u3); o.z = pk(u4, u5); o.w = pk(u6, u7);
            *(uint4*)&ujL[r][col] = o;
        } else {
            float4 ba = *(const float4*)&b1[k0];
            float4 bb = *(const float4*)&b1[k0 + 4];
            o.x = pk(ba.x - u0, ba.y - u1); o.y = pk(ba.z - u2, ba.w - u3);
            o.z = pk(bb.x - u4, bb.y - u5); o.w = pk(bb.z - u6, bb.w - u7);
            *(uint4*)&uinL[r - JH][col] = o;
        }
    }

    // ---- Weight fragments (f16). Identity k-map for L2, permuted for L3 ----
    F16x8U W2f[2][4];   // A-frag of mfma(W2^T, h1^T): W2[32s+8g+e][16n+c]
    #pragma unroll
    for (int s = 0; s < 2; ++s)
        #pragma unroll
        for (int n = 0; n < 4; ++n)
            #pragma unroll
            for (int e = 0; e < 8; ++e)
                W2f[s][n].v[e] = (_Float16)W2[(32*s + 8*g + e) * HID_ + 16*n + c];

    F16x8U W3g[2];      // B-frag, permuted k: hid = 32s + 16*(e>>2) + 4g + (e&3)
    #pragma unroll
    for (int s = 0; s < 2; ++s)
        #pragma unroll
        for (int e = 0; e < 8; ++e)
            W3g[s].v[e] = (_Float16)W3[(32*s + 16*(e>>2) + 4*g + (e&3)) * H_ + c];

    f32x4 b2v[4];
    #pragma unroll
    for (int n = 0; n < 4; ++n)
        b2v[n] = *(const f32x4*)&b2[16*n + 4*g];
    const float b3v = b3[c];

    // ---- i-mask bitmask ----
    const int* maskb = &mask[b * N_ + i0];
    u32 mrow = 0;
    #pragma unroll
    for (int tt = 0; tt < 4; ++tt) {
        int4 m = *(const int4*)&maskb[tt * 4];
        mrow |= (m.x ? 1u : 0u) << (4*tt);
        mrow |= (m.y ? 1u : 0u) << (4*tt + 1);
        mrow |= (m.z ? 1u : 0u) << (4*tt + 2);
        mrow |= (m.w ? 1u : 0u) << (4*tt + 3);
    }

    // ---- j-mask multipliers (compute-side): j = j0 + 64w + 16jj + 4g + q ----
    f32x4 mmul[4];
    #pragma unroll
    for (int jj = 0; jj < 4; ++jj) {
        int4 mj = *(const int4*)&mask[b * N_ + j0 + 64*w + 16*jj + 4*g];
        mmul[jj][0] = mj.x ? 0.f : 1.f;
        mmul[jj][1] = mj.y ? 0.f : 1.f;
        mmul[jj][2] = mj.z ? 0.f : 1.f;
        mmul[jj][3] = mj.w ? 0.f : 1.f;
    }

    // store-side mapping: lane covers plane p0=(l>>4)+4s, j = j0+64w+4*(l&15)
    float* const stBase = out + ((size_t)(b*H_ + (l >> 4)) << 20)
                              + ((size_t)i0 << 10)
                              + (size_t)(j0 + 64*w + 4*(l & 15));

    // bounce slice pointers (wave-private, no cross-wave access)
    float* const wslice  = bounce + w * (16 * PST);
    float* const depBase = wslice + c * PST + 4*g;        // deposit: plane c, chunk 4jj+g
    const float* const gathBase = wslice + (l >> 4) * PST + 4*(l & 15);

    __syncthreads();   // staging complete

    // ---- Hoist t-invariant pj fragments to registers (frees ujL) ----
    uint4 pjA[4], pjB[4];
    const int jb = c & 7;
    #pragma unroll
    for (int jj = 0; jj < 4; ++jj) {
        const int jrow = 64*w + 16*jj + c;
        pjA[jj] = *(const uint4*)&ujL[jrow][(g ^ jb) << 2];
        pjB[jj] = *(const uint4*)&ujL[jrow][((4 + g) ^ jb) << 2];
    }

    __syncthreads();   // all waves done reading ujL; bounce may now overwrite

    const f32x4 zero4 = { 0.f, 0.f, 0.f, 0.f };

    for (int t = 0; t < TI; ++t) {
        float* const rowp = stBase + ((size_t)t << 10);

        if ((mrow >> t) & 1) {     // whole i-row masked: plane-major zeros
            #pragma unroll
            for (int s = 0; s < 4; ++s)
                *(f32x4*)(rowp + ((size_t)s << 22)) = zero4;
            continue;
        }

        const int tb = t & 7;
        const uint4 uiA = *(const uint4*)&uinL[t][(g ^ tb) << 2];
        const uint4 uiB = *(const uint4*)&uinL[t][((4 + g) ^ tb) << 2];

        #pragma unroll
        for (int jj = 0; jj < 4; ++jj) {
            // Layer1: h1 = relu(u_j + (b1-u_i)) packed f16 — fragment-ready
            F16x8U A1[2];
            A1[0].u[0] = pkadd_relu(pjA[jj].x, uiA.x);
            A1[0].u[1] = pkadd_relu(pjA[jj].y, uiA.y);
            A1[0].u[2] = pkadd_relu(pjA[jj].z, uiA.z);
            A1[0].u[3] = pkadd_relu(pjA[jj].w, uiA.w);
            A1[1].u[0] = pkadd_relu(pjB[jj].x, uiB.x);
            A1[1].u[1] = pkadd_relu(pjB[jj].y, uiB.y);
            A1[1].u[2] = pkadd_relu(pjB[jj].z, uiB.z);
            A1[1].u[3] = pkadd_relu(pjB[jj].w, uiB.w);

            // Layer2 transposed: lane (g,c) gets h2pre[pair c][hid 16n+4g+q]
            f32x4 acc[4];
            #pragma unroll
            for (int n = 0; n < 4; ++n) {
                acc[n] = __builtin_amdgcn_mfma_f32_16x16x32_f16(W2f[0][n].v, A1[0].v, b2v[n], 0, 0, 0);
                acc[n] = __builtin_amdgcn_mfma_f32_16x16x32_f16(W2f[1][n].v, A1[1].v, acc[n], 0, 0, 0);
            }

            // Layer3 A-frag register-only via permuted k-map
            F16x8U A3[2];
            #pragma unroll
            for (int s = 0; s < 2; ++s) {
                A3[s].u[0] = pkcvt_relu(acc[2*s][0],     acc[2*s][1]);
                A3[s].u[1] = pkcvt_relu(acc[2*s][2],     acc[2*s][3]);
                A3[s].u[2] = pkcvt_relu(acc[2*s + 1][0], acc[2*s + 1][1]);
                A3[s].u[3] = pkcvt_relu(acc[2*s + 1][2], acc[2*s + 1][3]);
            }

            f32x4 acc3 = { b3v, b3v, b3v, b3v };
            acc3 = __builtin_amdgcn_mfma_f32_16x16x32_f16(A3[0].v, W3g[0].v, acc3, 0, 0, 0);
            acc3 = __builtin_amdgcn_mfma_f32_16x16x32_f16(A3[1].v, W3g[1].v, acc3, 0, 0, 0);

            // masked deposit into wave-private bounce (plane c, j-local 16jj+4g+q)
            *(f32x4*)(depBase + 16*jj) = acc3 * mmul[jj];
        }

        // gather plane-major + store: 4 instrs x (4 planes x 256B contiguous)
        // same-wave LDS dep -> compiler emits lgkmcnt wait; no barrier needed
        #pragma unroll
        for (int s = 0; s < 4; ++s) {
            f32x4 v = *(const f32x4*)(gathBase + s * (4 * PST));
            *(f32x4*)(rowp + ((size_t)s << 22)) = v;
        }
    }
}

extern "C" void kernel_launch(void* const* d_in, const int* in_sizes, int n_in,
                              void* d_out, int out_size, void* d_ws, size_t ws_size,
                              hipStream_t stream) {
    const float* pos  = (const float*)d_in[0];
    const int*   mask = (const int*)d_in[1];
    const float* W1   = (const float*)d_in[2];
    const float* b1   = (const float*)d_in[3];
    const float* W2   = (const float*)d_in[4];
    const float* b2   = (const float*)d_in[5];
    const float* W3   = (const float*)d_in[6];
    const float* b3   = (const float*)d_in[7];
    float* out = (float*)d_out;

    dim3 grid(N_ / JH, N_ / TI, B_);   // 4 x 64 x 4 = 1024 blocks
    RelativePositionalBias_kernel<<<grid, dim3(256), 0, stream>>>(
        pos, mask, W1, b1, W2, b2, W3, b3, out);
}